// Round 4
// baseline (603.963 us; speedup 1.0000x reference)
//
#include <hip/hip_runtime.h>
#include <cstdint>

#define NIN     2000
#define NRES    50
#define NOUT    500
#define TSTEPS  512
#define NBATCH  64
#define BT      32768   // NBATCH * TSTEPS
#define KPAD    2048    // W k-dim padded (zeros past 2000)
#define NPAD    64      // W n-dim padded (zeros past 50)
#define KSTEPS  63      // 63*32 = 2016 >= 2000; B zero-padded kills k in [2000,2016)
#define KCLAMP  1996    // last valid float4 base within a 2000-float U row

typedef __bf16 bf16x8 __attribute__((ext_vector_type(8)));
typedef float  f32x4  __attribute__((ext_vector_type(4)));

// tanh(x) = 1 - 2/(e^{2x}+1). Overflow-safe without clamping:
// x >> 0: e=inf -> rcp(inf)=0 -> 1 ; x << 0: e=0 -> 1-2 = -1. No NaN path.
__device__ __forceinline__ float fast_tanh(float x) {
  float e = __expf(2.0f * x);
  return fmaf(-2.0f, __builtin_amdgcn_rcpf(e + 1.0f), 1.0f);
}

// x = hi + lo with hi = RN-bf16(x) (lo then exact in fp32, Dekker), lo truncated
// to bf16 (error ~2^-16 relative to x). Inputs here are tanh outputs / small
// uniform weights: no inf/NaN, no rounding overflow.
__device__ __forceinline__ void bf16_split(float x, unsigned short& h, unsigned short& l) {
  unsigned u  = __float_as_uint(x);
  unsigned hb = (u + 0x7FFFu + ((u >> 16) & 1u)) & 0xFFFF0000u;
  h = (unsigned short)(hb >> 16);
  float lo = x - __uint_as_float(hb);
  l = (unsigned short)(__float_as_uint(lo) >> 16);
}

union ABfrag { unsigned short u16[8]; bf16x8 v; };

// ---- kernel 0: split W_in into zero-padded bf16 hi/lo planes [NPAD][KPAD] ----
__global__ __launch_bounds__(256) void prep_kernel(const float* __restrict__ Win,
                                                   unsigned short* __restrict__ Whi,
                                                   unsigned short* __restrict__ Wlo) {
  int idx = blockIdx.x * 256 + threadIdx.x;   // 0 .. NPAD*KPAD-1 (131072)
  int n = idx >> 11;                          // KPAD = 2^11
  int k = idx & (KPAD - 1);
  float x = (n < NRES && k < NIN) ? Win[n * NIN + k] : 0.0f;
  unsigned short h, l;
  bf16_split(x, h, l);
  Whi[idx] = h;
  Wlo[idx] = l;
}

// ---- kernel 1: P[bt][r] = sum_k tanh(U[bt][k]) * W_in[r][k] via 3-pass bf16 MFMA
// v2: register double-buffer for the B fragments + __launch_bounds__(256,2).
// v1 was allocated 36 VGPRs (compiler targeted 8 waves/SIMD that the 512-block
// grid can never reach) -> B loads serialized into ~8 L2 round-trips per k-step
// (measured 3390 cy/k-step vs ~350 cy of work; MfmaUtil 5.4%). Two named buffer
// structs swapped by reference in a 2-step unrolled loop (all indices static) give
// the loads a full k-step of latency cover; 2 waves/SIMD interleave the rest.
struct BFrags { bf16x8 h[4]; bf16x8 l[4]; };

__global__ __launch_bounds__(256, 2) void proj_mfma(const float* __restrict__ U,
                                                    const unsigned short* __restrict__ Whi,
                                                    const unsigned short* __restrict__ Wlo,
                                                    float* __restrict__ P) {
  const int wave = threadIdx.x >> 6;
  const int lane = threadIdx.x & 63;
  const int mrow = lane & 15;        // A row / C col within tile
  const int g    = lane >> 4;        // k-group (and C row group)
  const int g8   = g * 8;
  const int row0 = (blockIdx.x * 4 + wave) * 16;

  const float* __restrict__ u = U + (size_t)(row0 + mrow) * NIN;

  const unsigned short* bhp[4];
  const unsigned short* blp[4];
#pragma unroll
  for (int f = 0; f < 4; ++f) {
    const int n = f * 16 + mrow;     // B col
    bhp[f] = Whi + n * KPAD + g8;
    blp[f] = Wlo + n * KPAD + g8;
  }

  f32x4 acc[4] = {};

  // prologue: U ring (cur) + B fragments for step 0
  float4 ca = *(const float4*)(u + min(g8, KCLAMP));
  float4 cb = *(const float4*)(u + min(g8 + 4, KCLAMP));

  BFrags b0, b1;
#pragma unroll
  for (int f = 0; f < 4; ++f) {
    b0.h[f] = *(const bf16x8*)(bhp[f]);
    b0.l[f] = *(const bf16x8*)(blp[f]);
  }

  // one k-step: consume cur B frags + cur U regs, prefetch next-step B (at kn)
  // and next-step U. At s=62 the B prefetch reads k in [2016,2048) of the
  // zero-padded planes (in-bounds); U prefetch is address-clamped (safe dup).
  auto kstep = [&](int s, BFrags& cur, BFrags& nxt) {
    const int k0 = s * 32;
    const int kn = k0 + 32;
    float4 na = *(const float4*)(u + min(kn + g8, KCLAMP));
    float4 nb = *(const float4*)(u + min(kn + g8 + 4, KCLAMP));
#pragma unroll
    for (int f = 0; f < 4; ++f) {
      nxt.h[f] = *(const bf16x8*)(bhp[f] + kn);
      nxt.l[f] = *(const bf16x8*)(blp[f] + kn);
    }

    float t[8];
    t[0] = fast_tanh(ca.x); t[1] = fast_tanh(ca.y);
    t[2] = fast_tanh(ca.z); t[3] = fast_tanh(ca.w);
    t[4] = fast_tanh(cb.x); t[5] = fast_tanh(cb.y);
    t[6] = fast_tanh(cb.z); t[7] = fast_tanh(cb.w);

    ABfrag ah, al;
#pragma unroll
    for (int j = 0; j < 8; ++j) bf16_split(t[j], ah.u16[j], al.u16[j]);

#pragma unroll
    for (int f = 0; f < 4; ++f)
      acc[f] = __builtin_amdgcn_mfma_f32_16x16x32_bf16(ah.v, cur.h[f], acc[f], 0, 0, 0);
#pragma unroll
    for (int f = 0; f < 4; ++f)
      acc[f] = __builtin_amdgcn_mfma_f32_16x16x32_bf16(al.v, cur.h[f], acc[f], 0, 0, 0);
#pragma unroll
    for (int f = 0; f < 4; ++f)
      acc[f] = __builtin_amdgcn_mfma_f32_16x16x32_bf16(ah.v, cur.l[f], acc[f], 0, 0, 0);

    ca = na; cb = nb;
  };

  for (int sp = 0; sp < 31; ++sp) {
    kstep(2 * sp,     b0, b1);
    kstep(2 * sp + 1, b1, b0);
  }
  kstep(62, b0, b1);   // tail (prefetch lands in zero-pad, discarded)

  // C/D layout (verified m89): col = lane&15, row = (lane>>4)*4 + i
#pragma unroll
  for (int f = 0; f < 4; ++f) {
    const int col = f * 16 + mrow;
    if (col < NRES) {
#pragma unroll
      for (int i = 0; i < 4; ++i) {
        const int r = row0 + g * 4 + i;
        P[(size_t)r * NRES + col] = acc[f][i];
      }
    }
  }
}

// ---- kernel 2: sequential recurrence (one wave per batch row) + fused readout ----
// UNCHANGED from verified round-3 kernel (isolating the proj pipelining fix).
__global__ __launch_bounds__(64, 1) void recur_kernel(const float* __restrict__ P,
                                                      const float* __restrict__ W_res,
                                                      const float* __restrict__ W_out,
                                                      const float* __restrict__ bias,
                                                      float* __restrict__ out) {
  __shared__ float sbuf[64];
  const int b    = blockIdx.x;
  const int lane = threadIdx.x;
  const int r    = (lane < NRES) ? lane : 0;   // lanes 50-63 mirror lane 0 (never read back)

  // w[52]: this lane's W_res row, zero-padded at j=50,51 so the broadcast loop
  // can run 13 full float4s (sbuf[50],sbuf[51] hold finite mirror states; x0 = 0).
  float w[52];
#pragma unroll
  for (int j = 0; j < NRES; ++j) w[j] = W_res[r * NRES + j];
  w[50] = 0.0f; w[51] = 0.0f;

  const float* Pb = P + (size_t)b * TSTEPS * NRES;
  float state = 0.0f;

  float pring[16];
#pragma unroll
  for (int i = 0; i < 16; ++i) pring[i] = Pb[i * NRES + r];

#pragma unroll 16
  for (int t = 0; t < TSTEPS; ++t) {
    float pcur = pring[t & 15];
    // unconditional refill (keeps vmcnt counted; OOB-by-design reads stay in ws)
    pring[t & 15] = Pb[(t + 16) * NRES + r];

    sbuf[lane] = state;
    __syncthreads();   // single wave: lgkmcnt drain + cheap barrier

    // 13 broadcast quads (uniform-address ds_read_b128), 8-way split accumulator
    float a0 = pcur, a1 = 0.0f, a2 = 0.0f, a3 = 0.0f;
    float a4 = 0.0f, a5 = 0.0f, a6 = 0.0f, a7 = 0.0f;
#pragma unroll
    for (int q = 0; q < 12; q += 2) {
      float4 sA = *(const float4*)&sbuf[q * 4];
      float4 sB = *(const float4*)&sbuf[q * 4 + 4];
      a0 = fmaf(sA.x, w[4 * q + 0], a0);
      a1 = fmaf(sA.y, w[4 * q + 1], a1);
      a2 = fmaf(sA.z, w[4 * q + 2], a2);
      a3 = fmaf(sA.w, w[4 * q + 3], a3);
      a4 = fmaf(sB.x, w[4 * q + 4], a4);
      a5 = fmaf(sB.y, w[4 * q + 5], a5);
      a6 = fmaf(sB.z, w[4 * q + 6], a6);
      a7 = fmaf(sB.w, w[4 * q + 7], a7);
    }
    {
      float4 sA = *(const float4*)&sbuf[48];
      a0 = fmaf(sA.x, w[48], a0);
      a1 = fmaf(sA.y, w[49], a1);
      a2 = fmaf(sA.z, w[50], a2);   // w[50] = 0
      a3 = fmaf(sA.w, w[51], a3);   // w[51] = 0
    }
    state = fast_tanh(((a0 + a1) + (a2 + a3)) + ((a4 + a5) + (a6 + a7)));
    // next iteration's sbuf write is data-dependent on these reads (via state):
    // no extra barrier needed for WAR.
  }

  // readout: out[b][o] = tanh(sum_j state[j] * W_out[j][o] + bias[o])
  sbuf[lane] = state;
  __syncthreads();

#pragma unroll
  for (int kk = 0; kk < 8; ++kk) {
    int o = kk * 64 + lane;
    if (o < NOUT) {
      float a0 = bias[o];
      float a1 = 0.0f;
#pragma unroll
      for (int q = 0; q < 12; ++q) {
        float4 s4 = *(const float4*)&sbuf[q * 4];
        a0 = fmaf(s4.x, W_out[(4 * q + 0) * NOUT + o], a0);
        a1 = fmaf(s4.y, W_out[(4 * q + 1) * NOUT + o], a1);
        a0 = fmaf(s4.z, W_out[(4 * q + 2) * NOUT + o], a0);
        a1 = fmaf(s4.w, W_out[(4 * q + 3) * NOUT + o], a1);
      }
      {  // tail: j = 48, 49 only (W_out has exactly 50 rows)
        float4 s4 = *(const float4*)&sbuf[48];
        a0 = fmaf(s4.x, W_out[48 * NOUT + o], a0);
        a1 = fmaf(s4.y, W_out[49 * NOUT + o], a1);
      }
      out[b * NOUT + o] = fast_tanh(a0 + a1);
    }
  }
}

extern "C" void kernel_launch(void* const* d_in, const int* in_sizes, int n_in,
                              void* d_out, int out_size, void* d_ws, size_t ws_size,
                              hipStream_t stream) {
  const float* inputs = (const float*)d_in[0];
  const float* W_in   = (const float*)d_in[1];
  const float* W_res  = (const float*)d_in[2];
  const float* W_out  = (const float*)d_in[3];
  const float* bias   = (const float*)d_in[4];
  float* out = (float*)d_out;

  // ws layout: P f32 [32768][50] at 0 (6,553,600 B, fully overwritten by proj_mfma),
  // then Whi/Wlo bf16 [64][2048] (262,144 B each). Total ~7.08 MB.
  // NOTE: recur's prefetch ring deliberately over-reads P by <=3.2 KB into Whi.
  float* P = (float*)d_ws;
  unsigned short* Whi = (unsigned short*)((char*)d_ws + (size_t)BT * NRES * 4);
  unsigned short* Wlo = Whi + NPAD * KPAD;

  prep_kernel<<<(NPAD * KPAD) / 256, 256, 0, stream>>>(W_in, Whi, Wlo);
  proj_mfma<<<BT / 64, 256, 0, stream>>>(inputs, Whi, Wlo, P);
  recur_kernel<<<NBATCH, 64, 0, stream>>>(P, W_res, W_out, bias, out);
}

// Round 5
// 569.845 us; speedup vs baseline: 1.0599x; 1.0599x over previous
//
#include <hip/hip_runtime.h>
#include <cstdint>

#define NIN     2000
#define NRES    50
#define NOUT    500
#define TSTEPS  512
#define NBATCH  64
#define BT      32768   // NBATCH * TSTEPS
#define KSTEPS  63      // 63*32 = 2016 >= 2000; B zero-padded kills k in [2000,2016)
#define SPAD    64      // k-step slots in Bpk (slot 63 = zeros, read by last prefetch)
#define KCLAMP  1996    // last valid float4 base within a 2000-float U row

typedef __bf16 bf16x8 __attribute__((ext_vector_type(8)));
typedef float  f32x4  __attribute__((ext_vector_type(4)));

// tanh(x) = 1 - 2/(e^{2x}+1). Overflow-safe without clamping:
// x >> 0: e=inf -> rcp(inf)=0 -> 1 ; x << 0: e=0 -> 1-2 = -1. No NaN path.
__device__ __forceinline__ float fast_tanh(float x) {
  float e = __expf(2.0f * x);
  return fmaf(-2.0f, __builtin_amdgcn_rcpf(e + 1.0f), 1.0f);
}

// x = hi + lo with hi = RN-bf16(x) (lo then exact in fp32, Dekker), lo truncated
// to bf16 (error ~2^-16 relative to x). No inf/NaN inputs here.
__device__ __forceinline__ void bf16_split(float x, unsigned short& h, unsigned short& l) {
  unsigned u  = __float_as_uint(x);
  unsigned hb = (u + 0x7FFFu + ((u >> 16) & 1u)) & 0xFFFF0000u;
  h = (unsigned short)(hb >> 16);
  float lo = x - __uint_as_float(hb);
  l = (unsigned short)(__float_as_uint(lo) >> 16);
}

union ABfrag { unsigned short u16[8]; bf16x8 v; };

// ---- kernel 0: pack W_in into MFMA-staging order -------------------------------
// Bpk (bf16): [s][c][lane][8] with c = p*4 + f (p: 0=hi, 1=lo). For (s,c,l,j):
//   value = plane_p( W_in[n = f*16 + (l&15)][k = s*32 + (l>>4)*8 + j] ), 0 if OOB.
// Each k-step's 8 KB block is EXACTLY the LDS image proj stages (16B/lane
// coalesced loads, no transpose at stage time). s=63 slot is all zeros.
__global__ __launch_bounds__(256) void prep_kernel(const float* __restrict__ Win,
                                                   unsigned short* __restrict__ Bpk) {
  int tid  = blockIdx.x * 256 + threadIdx.x;  // 0 .. 32767 = ((s*8 + c)*64 + l)
  int l    = tid & 63;
  int rest = tid >> 6;
  int f    = rest & 3;
  int p    = (rest >> 2) & 1;
  int s    = rest >> 3;                       // 0..63
  int n    = f * 16 + (l & 15);
  int kb   = s * 32 + (l >> 4) * 8;
  unsigned short v[8];
#pragma unroll
  for (int j = 0; j < 8; ++j) {
    int k = kb + j;
    float x = (n < NRES && k < NIN) ? Win[n * NIN + k] : 0.0f;
    unsigned short h, lo;
    bf16_split(x, h, lo);
    v[j] = p ? lo : h;
  }
  *reinterpret_cast<uint4*>(Bpk + (size_t)tid * 8) = *reinterpret_cast<uint4*>(v);
}

// ---- kernel 1: P[bt][r] = sum_k tanh(U[bt][k]) * W_in[r][k], 3-pass bf16 MFMA ---
// v3: LDS 2-phase pipeline (T3-minimum + T14 issue-early/write-late).
// v2's register double-buffer was un-enforceable (scheduler sank the loads;
// VGPR stayed 44, MfmaUtil 5%). Now: per k-step, each wave issues its 2 coalesced
// 1KB B-stage loads + next U loads EARLY, computes from lds[cur], ds_writes the
// staged regs to lds[nxt], __syncthreads. B latency is covered by a full k-step
// by construction, and B is fetched once per BLOCK (4x less than per-wave).
// Wall per k-step = U HBM stream (16 KB/CU ~ 1600 cy); compute fits under it.
__global__ __launch_bounds__(256, 2) void proj_mfma(const float* __restrict__ U,
                                                    const unsigned short* __restrict__ Bpk,
                                                    float* __restrict__ P) {
  __shared__ __align__(16) unsigned short lds[2][4096];   // 2 x 8 KB
  const int wave = threadIdx.x >> 6;
  const int lane = threadIdx.x & 63;
  const int mrow = lane & 15;        // A row / C col within tile
  const int g    = lane >> 4;        // k-group (and C row group)
  const int g8   = g * 8;
  const int row0 = (blockIdx.x * 4 + wave) * 16;

  const float* __restrict__ u = U + (size_t)(row0 + mrow) * NIN;

  // this wave stages chunks c0,c1 of each 8-chunk (8 KB) k-step block
  const int c0 = wave * 2, c1 = c0 + 1;
  const unsigned short* src0 = Bpk + ((size_t)c0 * 64 + lane) * 8;  // +s*4096/step
  const unsigned short* src1 = Bpk + ((size_t)c1 * 64 + lane) * 8;
  unsigned short* dst0[2] = { &lds[0][(c0 * 64 + lane) * 8], &lds[1][(c0 * 64 + lane) * 8] };
  unsigned short* dst1[2] = { &lds[0][(c1 * 64 + lane) * 8], &lds[1][(c1 * 64 + lane) * 8] };

  f32x4 acc[4] = {};

  // prologue: stage s=0 into lds[0], load U step 0
  {
    uint4 s0 = *reinterpret_cast<const uint4*>(src0);
    uint4 s1 = *reinterpret_cast<const uint4*>(src1);
    *reinterpret_cast<uint4*>(dst0[0]) = s0;
    *reinterpret_cast<uint4*>(dst1[0]) = s1;
  }
  float4 ca = *(const float4*)(u + min(g8, KCLAMP));
  float4 cb = *(const float4*)(u + min(g8 + 4, KCLAMP));
  __syncthreads();

  for (int s = 0; s < KSTEPS; ++s) {
    const int cur = s & 1, nxt = cur ^ 1;
    const int kn = s * 32 + 32;

    // issue next-step loads EARLY: B stage (s=62 reads the zero slot 63) + U ring
    uint4 n0 = *reinterpret_cast<const uint4*>(src0 + (size_t)(s + 1) * 4096);
    uint4 n1 = *reinterpret_cast<const uint4*>(src1 + (size_t)(s + 1) * 4096);
    float4 na = *(const float4*)(u + min(kn + g8, KCLAMP));
    float4 nb = *(const float4*)(u + min(kn + g8 + 4, KCLAMP));

    // fragments for this step from lds[cur] (16B/lane contiguous, conflict-free)
    bf16x8 bh[4], bl[4];
#pragma unroll
    for (int f = 0; f < 4; ++f) {
      bh[f] = *(const bf16x8*)&lds[cur][(f * 64 + lane) * 8];        // c = f     (hi)
      bl[f] = *(const bf16x8*)&lds[cur][((4 + f) * 64 + lane) * 8];  // c = 4 + f (lo)
    }

    float t[8];
    t[0] = fast_tanh(ca.x); t[1] = fast_tanh(ca.y);
    t[2] = fast_tanh(ca.z); t[3] = fast_tanh(ca.w);
    t[4] = fast_tanh(cb.x); t[5] = fast_tanh(cb.y);
    t[6] = fast_tanh(cb.z); t[7] = fast_tanh(cb.w);

    ABfrag ah, al;
#pragma unroll
    for (int j = 0; j < 8; ++j) bf16_split(t[j], ah.u16[j], al.u16[j]);

#pragma unroll
    for (int f = 0; f < 4; ++f)
      acc[f] = __builtin_amdgcn_mfma_f32_16x16x32_bf16(ah.v, bh[f], acc[f], 0, 0, 0);
#pragma unroll
    for (int f = 0; f < 4; ++f)
      acc[f] = __builtin_amdgcn_mfma_f32_16x16x32_bf16(al.v, bh[f], acc[f], 0, 0, 0);
#pragma unroll
    for (int f = 0; f < 4; ++f)
      acc[f] = __builtin_amdgcn_mfma_f32_16x16x32_bf16(ah.v, bl[f], acc[f], 0, 0, 0);

    // write-late: staged regs -> lds[nxt] (the buffer all waves finished reading
    // at the END of step s-1; the barrier below publishes it for step s+1)
    *reinterpret_cast<uint4*>(dst0[nxt]) = n0;
    *reinterpret_cast<uint4*>(dst1[nxt]) = n1;
    __syncthreads();

    ca = na; cb = nb;
  }

  // C/D layout (verified m89): col = lane&15, row = (lane>>4)*4 + i
#pragma unroll
  for (int f = 0; f < 4; ++f) {
    const int col = f * 16 + mrow;
    if (col < NRES) {
#pragma unroll
      for (int i = 0; i < 4; ++i) {
        const int r = row0 + g * 4 + i;
        P[(size_t)r * NRES + col] = acc[f][i];
      }
    }
  }
}

// ---- kernel 2: sequential recurrence (one wave per batch row) + fused readout ----
// v4: NO __syncthreads in the step loop. v3's __syncthreads emitted
// s_waitcnt vmcnt(0) every step, draining the 16-deep P-ring -> one exposed
// IF$ round-trip per step (measured ~703 cy/step). A single-wave block needs
// only LDS program-order (lgkmcnt, compiler-inserted; wave_barrier pins the
// scheduler) for the sbuf broadcast; the WAR on sbuf is protected by the data
// dependency through `state`. vmcnt now stays counted -> ring finally works.
__global__ __launch_bounds__(64, 1) void recur_kernel(const float* __restrict__ P,
                                                      const float* __restrict__ W_res,
                                                      const float* __restrict__ W_out,
                                                      const float* __restrict__ bias,
                                                      float* __restrict__ out) {
  __shared__ float sbuf[64];
  const int b    = blockIdx.x;
  const int lane = threadIdx.x;
  const int r    = (lane < NRES) ? lane : 0;   // lanes 50-63 mirror lane 0 (never read back)

  // w[52]: this lane's W_res row, zero-padded at j=50,51 so the broadcast loop
  // can run 13 full float4s (sbuf[50],sbuf[51] hold finite mirror states; x0 = 0).
  float w[52];
#pragma unroll
  for (int j = 0; j < NRES; ++j) w[j] = W_res[r * NRES + j];
  w[50] = 0.0f; w[51] = 0.0f;

  const float* Pb = P + (size_t)b * TSTEPS * NRES;
  float state = 0.0f;

  float pring[16];
#pragma unroll
  for (int i = 0; i < 16; ++i) pring[i] = Pb[i * NRES + r];

#pragma unroll 16
  for (int t = 0; t < TSTEPS; ++t) {
    float pcur = pring[t & 15];
    // unconditional refill (counted vmcnt; tail over-reads <=3.2 KB into Bpk, in-ws)
    pring[t & 15] = Pb[(t + 16) * NRES + r];

    sbuf[lane] = state;
    __builtin_amdgcn_wave_barrier();   // pin write-before-reads scheduling (no-op inst)

    // 13 broadcast quads (uniform-address ds_read_b128), 8-way split accumulator
    float a0 = pcur, a1 = 0.0f, a2 = 0.0f, a3 = 0.0f;
    float a4 = 0.0f, a5 = 0.0f, a6 = 0.0f, a7 = 0.0f;
#pragma unroll
    for (int q = 0; q < 12; q += 2) {
      float4 sA = *(const float4*)&sbuf[q * 4];
      float4 sB = *(const float4*)&sbuf[q * 4 + 4];
      a0 = fmaf(sA.x, w[4 * q + 0], a0);
      a1 = fmaf(sA.y, w[4 * q + 1], a1);
      a2 = fmaf(sA.z, w[4 * q + 2], a2);
      a3 = fmaf(sA.w, w[4 * q + 3], a3);
      a4 = fmaf(sB.x, w[4 * q + 4], a4);
      a5 = fmaf(sB.y, w[4 * q + 5], a5);
      a6 = fmaf(sB.z, w[4 * q + 6], a6);
      a7 = fmaf(sB.w, w[4 * q + 7], a7);
    }
    {
      float4 sA = *(const float4*)&sbuf[48];
      a0 = fmaf(sA.x, w[48], a0);
      a1 = fmaf(sA.y, w[49], a1);
      a2 = fmaf(sA.z, w[50], a2);   // w[50] = 0
      a3 = fmaf(sA.w, w[51], a3);   // w[51] = 0
    }
    state = fast_tanh(((a0 + a1) + (a2 + a3)) + ((a4 + a5) + (a6 + a7)));
    // next sbuf[lane]=state is data-dependent on these reads -> WAR safe, no barrier
  }

  // readout: out[b][o] = tanh(sum_j state[j] * W_out[j][o] + bias[o])
  sbuf[lane] = state;
  __builtin_amdgcn_wave_barrier();

#pragma unroll
  for (int kk = 0; kk < 8; ++kk) {
    int o = kk * 64 + lane;
    if (o < NOUT) {
      float a0 = bias[o];
      float a1 = 0.0f;
#pragma unroll
      for (int q = 0; q < 12; ++q) {
        float4 s4 = *(const float4*)&sbuf[q * 4];
        a0 = fmaf(s4.x, W_out[(4 * q + 0) * NOUT + o], a0);
        a1 = fmaf(s4.y, W_out[(4 * q + 1) * NOUT + o], a1);
        a0 = fmaf(s4.z, W_out[(4 * q + 2) * NOUT + o], a0);
        a1 = fmaf(s4.w, W_out[(4 * q + 3) * NOUT + o], a1);
      }
      {  // tail: j = 48, 49 only (W_out has exactly 50 rows)
        float4 s4 = *(const float4*)&sbuf[48];
        a0 = fmaf(s4.x, W_out[48 * NOUT + o], a0);
        a1 = fmaf(s4.y, W_out[49 * NOUT + o], a1);
      }
      out[b * NOUT + o] = fast_tanh(a0 + a1);
    }
  }
}

extern "C" void kernel_launch(void* const* d_in, const int* in_sizes, int n_in,
                              void* d_out, int out_size, void* d_ws, size_t ws_size,
                              hipStream_t stream) {
  const float* inputs = (const float*)d_in[0];
  const float* W_in   = (const float*)d_in[1];
  const float* W_res  = (const float*)d_in[2];
  const float* W_out  = (const float*)d_in[3];
  const float* bias   = (const float*)d_in[4];
  float* out = (float*)d_out;

  // ws layout: P f32 [32768][50] at 0 (6,553,600 B, fully overwritten by proj_mfma),
  // then Bpk bf16 [64][8][64][8] (524,288 B). Total ~7.08 MB.
  // NOTE: recur's prefetch ring deliberately over-reads P by <=3.2 KB into Bpk.
  float* P = (float*)d_ws;
  unsigned short* Bpk = (unsigned short*)((char*)d_ws + (size_t)BT * NRES * 4);

  prep_kernel<<<128, 256, 0, stream>>>(W_in, Bpk);
  proj_mfma<<<BT / 64, 256, 0, stream>>>(inputs, Bpk, P);
  recur_kernel<<<NBATCH, 64, 0, stream>>>(P, W_res, W_out, bias, out);
}

// Round 6
// 483.344 us; speedup vs baseline: 1.2495x; 1.1790x over previous
//
#include <hip/hip_runtime.h>
#include <cstdint>

#define NIN     2000
#define NRES    50
#define NOUT    500
#define TSTEPS  512
#define NBATCH  64
#define BT      32768   // NBATCH * TSTEPS
#define KSTEPS  63      // 63*32 = 2016 >= 2000; B zero-padded kills k in [2000,2016)

typedef __bf16 bf16x8 __attribute__((ext_vector_type(8)));
typedef float  f32x4  __attribute__((ext_vector_type(4)));

// tanh(x) = 1 - 2/(e^{2x}+1). Overflow-safe without clamping:
// x >> 0: e=inf -> rcp(inf)=0 -> 1 ; x << 0: e=0 -> 1-2 = -1. No NaN path.
__device__ __forceinline__ float fast_tanh(float x) {
  float e = __expf(2.0f * x);
  return fmaf(-2.0f, __builtin_amdgcn_rcpf(e + 1.0f), 1.0f);
}

// x = hi + lo with hi = RN-bf16(x) (lo then exact in fp32, Dekker), lo truncated
// to bf16 (error ~2^-16 relative to x). No inf/NaN inputs here.
__device__ __forceinline__ void bf16_split(float x, unsigned short& h, unsigned short& l) {
  unsigned u  = __float_as_uint(x);
  unsigned hb = (u + 0x7FFFu + ((u >> 16) & 1u)) & 0xFFFF0000u;
  h = (unsigned short)(hb >> 16);
  float lo = x - __uint_as_float(hb);
  l = (unsigned short)(__float_as_uint(lo) >> 16);
}

union ABfrag { unsigned short u16[8]; bf16x8 v; };

// ---- kernel 0: pack W_in into MFMA-staging order (UNCHANGED, verified) --------
// Bpk (bf16): [s][c][lane][8] with c = p*4 + f (p: 0=hi, 1=lo). For (s,c,l,j):
//   value = plane_p( W_in[n = f*16 + (l&15)][k = s*32 + (l>>4)*8 + j] ), 0 if OOB.
// s=63 slot is all zeros (read by the last prefetch, never contributes).
__global__ __launch_bounds__(256) void prep_kernel(const float* __restrict__ Win,
                                                   unsigned short* __restrict__ Bpk) {
  int tid  = blockIdx.x * 256 + threadIdx.x;  // 0 .. 32767 = ((s*8 + c)*64 + l)
  int l    = tid & 63;
  int rest = tid >> 6;
  int f    = rest & 3;
  int p    = (rest >> 2) & 1;
  int s    = rest >> 3;                       // 0..63
  int n    = f * 16 + (l & 15);
  int kb   = s * 32 + (l >> 4) * 8;
  unsigned short v[8];
#pragma unroll
  for (int j = 0; j < 8; ++j) {
    int k = kb + j;
    float x = (n < NRES && k < NIN) ? Win[n * NIN + k] : 0.0f;
    unsigned short h, lo;
    bf16_split(x, h, lo);
    v[j] = p ? lo : h;
  }
  *reinterpret_cast<uint4*>(Bpk + (size_t)tid * 8) = *reinterpret_cast<uint4*>(v);
}

// ---- kernel 1: P[bt][r] = sum_k tanh(U[bt][k]) * W_in[r][k], 3-pass bf16 MFMA ---
// v4: COALESCED U through LDS. v3's direct per-lane U loads had lane addresses
// spread over 16 rows x 4 disjoint 128B chunks -> ~64 partial 64B transactions
// per instruction; the TA/L1 serialization (~2K cy/CU/step) was the 2.2 us/step
// wall. Now loader thread (rw=tid>>2, koct=tid&3) reads 8 CONSECUTIVE floats of
// one row (4-lane groups = contiguous 128 B), tanh+splits on the write side, and
// stores fragment-ordered bf16 planes to LDS; MFMA lanes read contiguous 16 B.
// U is carried 2 steps in regs (issue at s for s+2, LDS-write at s+1) so its
// vmcnt wait is always a full k-step deep; B keeps the verified 1-step stage.
// Per-CU step budget: U stream 16 KB ~1600 cy (HBM-bound) > LDS ~900 > MFMA ~470.
__global__ __launch_bounds__(256, 2) void proj_mfma(const float* __restrict__ U,
                                                    const unsigned short* __restrict__ Bpk,
                                                    float* __restrict__ P) {
  __shared__ __align__(16) unsigned short ldsA[2][2][2048];  // [stage][hi/lo][4w*64l*8]
  __shared__ __align__(16) unsigned short ldsB[2][4096];     // [stage][8c*64l*8]

  const int tid  = threadIdx.x;
  const int wave = tid >> 6;
  const int lane = tid & 63;
  const int mrow = lane & 15;        // A row / C col within tile
  const int g    = lane >> 4;        // k-octet (and C row group)
  const int row0 = blockIdx.x * 64 + wave * 16;

  // loader role: row rw (0..63) within block, k-octet koct (0..3) within k-step
  const int rw   = tid >> 2;
  const int koct = tid & 3;
  const float* __restrict__ urow = U + (size_t)(blockIdx.x * 64 + rw) * NIN;
  const int kfix  = koct * 8;
  // fragment slot this loader fills: wave-region rw>>4, lane-slot koct*16 + rw%16
  const int aslot = (rw >> 4) * 512 + ((koct << 4) | (rw & 15)) * 8;

  // B stage role (verified in v3): this thread stages chunks c0,c1
  const int c0 = wave * 2, c1 = c0 + 1;
  const unsigned short* srcB0 = Bpk + ((size_t)c0 * 64 + lane) * 8;  // +s*4096/step
  const unsigned short* srcB1 = Bpk + ((size_t)c1 * 64 + lane) * 8;
  const int bslot0 = (c0 * 64 + lane) * 8;
  const int bslot1 = (c1 * 64 + lane) * 8;

  f32x4 acc[4] = {};

  // tanh + hi/lo split + fragment-ordered LDS write of one staged U octet
  auto stageA = [&](int st, float4 a0, float4 a1) {
    float t[8];
    t[0] = fast_tanh(a0.x); t[1] = fast_tanh(a0.y);
    t[2] = fast_tanh(a0.z); t[3] = fast_tanh(a0.w);
    t[4] = fast_tanh(a1.x); t[5] = fast_tanh(a1.y);
    t[6] = fast_tanh(a1.z); t[7] = fast_tanh(a1.w);
    ABfrag h, l;
#pragma unroll
    for (int j = 0; j < 8; ++j) bf16_split(t[j], h.u16[j], l.u16[j]);
    *reinterpret_cast<bf16x8*>(&ldsA[st][0][aslot]) = h.v;
    *reinterpret_cast<bf16x8*>(&ldsA[st][1][aslot]) = l.v;
  };

  // prologue: stage step 0 into stage 0; carry U(step 1) in regs
  {
    float4 a0 = *(const float4*)(urow + kfix);        // k in [0,32): in bounds
    float4 a1 = *(const float4*)(urow + kfix + 4);
    uint4  b0 = *(const uint4*)(srcB0);
    uint4  b1 = *(const uint4*)(srcB1);
    stageA(0, a0, a1);
    *reinterpret_cast<uint4*>(&ldsB[0][bslot0]) = b0;
    *reinterpret_cast<uint4*>(&ldsB[0][bslot1]) = b1;
  }
  float4 ca = *(const float4*)(urow + 32 + kfix);     // k in [32,64): in bounds
  float4 cb = *(const float4*)(urow + 32 + kfix + 4);
  __syncthreads();

  for (int s = 0; s < KSTEPS; ++s) {
    const int cur = s & 1, nxt = cur ^ 1;

    // issue-early: U(s+2) (clamped; k>=2000 reads real-but-unused data that
    // multiplies B's zero pad) and B(s+1) (slot 63 = zeros)
    const int kb = (s + 2) * 32 + kfix;
    float4 na = *(const float4*)(urow + min(kb, 1992));
    float4 nb = *(const float4*)(urow + min(kb + 4, 1996));
    uint4  n0 = *(const uint4*)(srcB0 + (size_t)(s + 1) * 4096);
    uint4  n1 = *(const uint4*)(srcB1 + (size_t)(s + 1) * 4096);

    // compute step s from stage cur (all reads contiguous 16 B/lane)
    bf16x8 ah = *(const bf16x8*)&ldsA[cur][0][wave * 512 + lane * 8];
    bf16x8 al = *(const bf16x8*)&ldsA[cur][1][wave * 512 + lane * 8];
    bf16x8 bh[4], bl[4];
#pragma unroll
    for (int f = 0; f < 4; ++f) {
      bh[f] = *(const bf16x8*)&ldsB[cur][(f * 64 + lane) * 8];
      bl[f] = *(const bf16x8*)&ldsB[cur][((4 + f) * 64 + lane) * 8];
    }

#pragma unroll
    for (int f = 0; f < 4; ++f)
      acc[f] = __builtin_amdgcn_mfma_f32_16x16x32_bf16(ah, bh[f], acc[f], 0, 0, 0);
#pragma unroll
    for (int f = 0; f < 4; ++f)
      acc[f] = __builtin_amdgcn_mfma_f32_16x16x32_bf16(al, bh[f], acc[f], 0, 0, 0);
#pragma unroll
    for (int f = 0; f < 4; ++f)
      acc[f] = __builtin_amdgcn_mfma_f32_16x16x32_bf16(ah, bl[f], acc[f], 0, 0, 0);

    // write-late: stage s+1 = carried U (loaded a full step ago) + just-issued B
    stageA(nxt, ca, cb);
    *reinterpret_cast<uint4*>(&ldsB[nxt][bslot0]) = n0;
    *reinterpret_cast<uint4*>(&ldsB[nxt][bslot1]) = n1;
    __syncthreads();

    ca = na; cb = nb;
  }

  // C/D layout (verified m89): col = lane&15, row = (lane>>4)*4 + i
#pragma unroll
  for (int f = 0; f < 4; ++f) {
    const int col = f * 16 + mrow;
    if (col < NRES) {
#pragma unroll
      for (int i = 0; i < 4; ++i) {
        const int r = row0 + g * 4 + i;
        P[(size_t)r * NRES + col] = acc[f][i];
      }
    }
  }
}

// ---- kernel 2: sequential recurrence (one wave per batch row) + fused readout ----
// v5: PURE-REGISTER broadcast via readlane; zero LDS ops in the step loop.
// Evidence: v1 (readlane, ring-bugged) 221 us beat v2 (LDS bcast, same bug) 236;
// the LDS write->lgkmcnt(0)->read round trip (~200-300 cy) sits on the serial
// chain every step, readlane does not. Keep the verified unconditional 16-deep
// ring (counted vmcnt). 8-way split accumulators for readlane/FMA ILP.
__device__ __forceinline__ float rl(float v, int j) {
  return __uint_as_float(__builtin_amdgcn_readlane(__float_as_uint(v), j));
}

__global__ __launch_bounds__(64, 1) void recur_kernel(const float* __restrict__ P,
                                                      const float* __restrict__ W_res,
                                                      const float* __restrict__ W_out,
                                                      const float* __restrict__ bias,
                                                      float* __restrict__ out) {
  __shared__ float sbuf[64];
  const int b    = blockIdx.x;
  const int lane = threadIdx.x;
  const int r    = (lane < NRES) ? lane : 0;   // lanes 50-63 mirror lane 0 (never read)

  float w[NRES];
#pragma unroll
  for (int j = 0; j < NRES; ++j) w[j] = W_res[r * NRES + j];

  const float* Pb = P + (size_t)b * TSTEPS * NRES;
  float state = 0.0f;

  float pring[16];
#pragma unroll
  for (int i = 0; i < 16; ++i) pring[i] = Pb[i * NRES + r];

#pragma unroll 16
  for (int t = 0; t < TSTEPS; ++t) {
    float pcur = pring[t & 15];
    // unconditional refill (counted vmcnt; tail over-reads <=1.6 KB into Bpk, in-ws)
    pring[t & 15] = Pb[(t + 16) * NRES + r];

    float a0 = pcur, a1 = 0.0f, a2 = 0.0f, a3 = 0.0f;
    float a4 = 0.0f, a5 = 0.0f, a6 = 0.0f, a7 = 0.0f;
#pragma unroll
    for (int j = 0; j < 48; j += 8) {
      a0 = fmaf(rl(state, j + 0), w[j + 0], a0);
      a1 = fmaf(rl(state, j + 1), w[j + 1], a1);
      a2 = fmaf(rl(state, j + 2), w[j + 2], a2);
      a3 = fmaf(rl(state, j + 3), w[j + 3], a3);
      a4 = fmaf(rl(state, j + 4), w[j + 4], a4);
      a5 = fmaf(rl(state, j + 5), w[j + 5], a5);
      a6 = fmaf(rl(state, j + 6), w[j + 6], a6);
      a7 = fmaf(rl(state, j + 7), w[j + 7], a7);
    }
    a0 = fmaf(rl(state, 48), w[48], a0);
    a1 = fmaf(rl(state, 49), w[49], a1);
    state = fast_tanh(((a0 + a1) + (a2 + a3)) + ((a4 + a5) + (a6 + a7)));
  }

  // readout: out[b][o] = tanh(sum_j state[j] * W_out[j][o] + bias[o])  (one-time)
  sbuf[lane] = state;
  __syncthreads();

#pragma unroll
  for (int kk = 0; kk < 8; ++kk) {
    int o = kk * 64 + lane;
    if (o < NOUT) {
      float a0 = bias[o];
      float a1 = 0.0f;
#pragma unroll
      for (int q = 0; q < 12; ++q) {
        float4 s4 = *(const float4*)&sbuf[q * 4];
        a0 = fmaf(s4.x, W_out[(4 * q + 0) * NOUT + o], a0);
        a1 = fmaf(s4.y, W_out[(4 * q + 1) * NOUT + o], a1);
        a0 = fmaf(s4.z, W_out[(4 * q + 2) * NOUT + o], a0);
        a1 = fmaf(s4.w, W_out[(4 * q + 3) * NOUT + o], a1);
      }
      {  // tail: j = 48, 49 only (W_out has exactly 50 rows)
        float4 s4 = *(const float4*)&sbuf[48];
        a0 = fmaf(s4.x, W_out[48 * NOUT + o], a0);
        a1 = fmaf(s4.y, W_out[49 * NOUT + o], a1);
      }
      out[b * NOUT + o] = fast_tanh(a0 + a1);
    }
  }
}

extern "C" void kernel_launch(void* const* d_in, const int* in_sizes, int n_in,
                              void* d_out, int out_size, void* d_ws, size_t ws_size,
                              hipStream_t stream) {
  const float* inputs = (const float*)d_in[0];
  const float* W_in   = (const float*)d_in[1];
  const float* W_res  = (const float*)d_in[2];
  const float* W_out  = (const float*)d_in[3];
  const float* bias   = (const float*)d_in[4];
  float* out = (float*)d_out;

  // ws layout: P f32 [32768][50] at 0 (6,553,600 B, fully overwritten by proj_mfma),
  // then Bpk bf16 [64][8][64][8] (524,288 B). Total ~7.08 MB.
  // NOTE: recur's prefetch ring deliberately over-reads P by <=1.6 KB into Bpk.
  float* P = (float*)d_ws;
  unsigned short* Bpk = (unsigned short*)((char*)d_ws + (size_t)BT * NRES * 4);

  prep_kernel<<<128, 256, 0, stream>>>(W_in, Bpk);
  proj_mfma<<<BT / 64, 256, 0, stream>>>(inputs, Bpk, P);
  recur_kernel<<<NBATCH, 64, 0, stream>>>(P, W_res, W_out, bias, out);
}